// Round 12
// baseline (49.023 us; speedup 1.0000x reference)
//
#include <hip/hip_runtime.h>
#include <math.h>

#define NBATCH 8192
#define NIN 64
#define NOUT 64
#define NG 17

typedef float f32x4 __attribute__((ext_vector_type(4)));

#define OUT_ELEMS   (NBATCH * NOUT)
#define EDGE_ELEMS  (NBATCH * NIN * NOUT)

#define WT_U16      (NIN * NG * NOUT)          // 69632 bf16 elems, layout [i][g][o]
#define SC_U16      (NIN * NOUT)               // 4096 bf16 elems, layout [i][o]
#define SHMEM_BYTES ((WT_U16 + SC_U16) * 2)    // 147456 B dynamic LDS

__device__ __forceinline__ f32x4 bf4_to_f4(ushort4 h) {
    f32x4 f;
    f.x = __uint_as_float(((unsigned)h.x) << 16);
    f.y = __uint_as_float(((unsigned)h.y) << 16);
    f.z = __uint_as_float(((unsigned)h.z) << 16);
    f.w = __uint_as_float(((unsigned)h.w) << 16);
    return f;
}

// One 512-thread block per CU (grid=256), persistent over 32 batch rows.
// ALL weights live in LDS (bf16): the store loop has NO global loads ->
// pure store stream on the VMEM pipe (fill-like), LDS feeds operands.
__global__ __launch_bounds__(512) void kan_kernel(
    const float* __restrict__ x,      // [B, 64]
    const float* __restrict__ scale,  // [64, 64]
    const float* __restrict__ W,      // [64, 64, 17] original layout
    const float* __restrict__ bias,   // [64]
    float* __restrict__ out,          // [B, 64]
    float* __restrict__ edge,         // [B, 64, 64]
    float* __restrict__ basis)        // [B, 64, 17]
{
    extern __shared__ unsigned short s_dyn[];     // wt[69632] | sc[4096]
    unsigned short* s_wt = s_dyn;
    unsigned short* s_sc = s_dyn + WT_U16;
    __shared__ f32x4 s_meta[8][64];               // {silu, tw0, tw1, bits(g0c|g1c<<16)}

    const int tid  = threadIdx.x;
    const int wave = tid >> 6;
    const int lane = tid & 63;
    const int row0 = blockIdx.x * 32;             // 256 blocks x 32 rows = 8192

    // ---- prefetch this wave's 4 x-rows + bias (overlaps staging) ----
    float xr[4];
    #pragma unroll
    for (int r = 0; r < 4; ++r)
        xr[r] = x[(row0 + r * 8 + wave) * NIN + lane];
    f32x4 bi4 = *(const f32x4*)(bias + (lane & 15) * 4);

    // ---- stage W -> LDS bf16 [i][g][o] (each thread packs 2 adjacent o) ----
    for (int p = tid; p < WT_U16 / 2; p += 512) {
        int o2  = p & 31;          // o = 2*o2
        int rem = p >> 5;          // i*17 + g
        int g   = rem % 17;
        int i   = rem / 17;
        int gb  = (i * NOUT + o2 * 2) * NG + g;
        unsigned lo = __float_as_uint(W[gb])      >> 16;   // bf16 truncate
        unsigned hi = __float_as_uint(W[gb + NG]) >> 16;
        ((unsigned*)s_wt)[p] = lo | (hi << 16);
    }
    // ---- stage scale -> LDS bf16 [i][o] ----
    for (int p = tid; p < SC_U16 / 2; p += 512) {
        unsigned lo = __float_as_uint(scale[2 * p])     >> 16;
        unsigned hi = __float_as_uint(scale[2 * p + 1]) >> 16;
        ((unsigned*)s_sc)[p] = lo | (hi << 16);
    }
    __syncthreads();

    for (int r = 0; r < 4; ++r) {
        const int b = row0 + r * 8 + wave;

        // ---- phase 1: per-input meta (lane == i); same-wave LDS, no barrier ----
        {
            float xv  = xr[r];
            float sig = 1.0f / (1.0f + __expf(-xv));
            float sl  = xv * sig;
            float u   = (xv + 2.5f) * 3.2f;       // spacing = 5/16 exact
            float g0f = floorf(u);
            float t   = u - g0f;
            int   g0  = (int)g0f;
            float tw0 = ((unsigned)g0       < 17u) ? (1.0f - t) : 0.0f;
            float tw1 = ((unsigned)(g0 + 1) < 17u) ? t          : 0.0f;
            int g0c = min(max(g0, 0), 16);
            int g1c = min(max(g0 + 1, 0), 16);
            f32x4 m;
            m.x = sl; m.y = tw0; m.z = tw1;
            m.w = __uint_as_float((unsigned)g0c | ((unsigned)g1c << 16));
            s_meta[wave][lane] = m;
        }

        // ---- phase 2: basis writes (272 f32x4 per row), no global loads ----
        {
            float* brow = basis + (size_t)b * (NIN * NG);
            #pragma unroll
            for (int k = 0; k < 5; ++k) {
                int f4 = k * 64 + lane;
                if (f4 < 272) {
                    int p0 = f4 * 4;
                    f32x4 v;
                    #pragma unroll
                    for (int e = 0; e < 4; ++e) {
                        int p = p0 + e;
                        int i = (int)((unsigned)p / 17u);
                        int g = p - i * 17;
                        f32x4 m = s_meta[wave][i];
                        unsigned gg = __float_as_uint(m.w);
                        int g0c = (int)(gg & 0xffffu);
                        int g1c = (int)(gg >> 16);
                        v[e] = ((g == g0c) ? m.y : 0.0f) + ((g == g1c) ? m.z : 0.0f);
                    }
                    *(f32x4*)(brow + p0) = v;
                }
            }
        }

        // ---- phase 3: edge stores — LDS-fed, zero VMEM loads in loop ----
        f32x4 acc = {0.f, 0.f, 0.f, 0.f};
        float* erow = edge + (size_t)b * (NIN * NOUT);
        const int iq   = lane >> 4;
        const int ocol = (lane & 15) * 4;
        #pragma unroll 4
        for (int ib = 0; ib < NIN; ib += 4) {
            int i = ib + iq;
            f32x4 m = s_meta[wave][i];
            unsigned gg = __float_as_uint(m.w);
            int g0c = (int)(gg & 0xffffu);
            int g1c = (int)(gg >> 16);
            const unsigned short* wbase = s_wt + i * (NG * NOUT) + ocol;
            f32x4 w0 = bf4_to_f4(*(const ushort4*)(wbase + g0c * NOUT));
            f32x4 w1 = bf4_to_f4(*(const ushort4*)(wbase + g1c * NOUT));
            f32x4 sc = bf4_to_f4(*(const ushort4*)(s_sc + i * NOUT + ocol));
            f32x4 v = m.x * sc + m.y * w0 + m.z * w1;
            // erow + i*64 + ocol == erow + ib*64 + lane*4  (contiguous 1KB/wave)
            *(f32x4*)(erow + ib * NOUT + lane * 4) = v;
            acc += v;
        }
        #pragma unroll
        for (int e = 0; e < 4; ++e) {
            float a = acc[e];
            a += __shfl_xor(a, 16);
            a += __shfl_xor(a, 32);
            acc[e] = a;
        }
        if (lane < 16) {
            f32x4 rr = acc * 0.125f + bi4;        // 1/sqrt(64) = 0.125 exact
            *(f32x4*)(out + (size_t)b * NOUT + lane * 4) = rr;
        }
    }
}

extern "C" void kernel_launch(void* const* d_in, const int* in_sizes, int n_in,
                              void* d_out, int out_size, void* d_ws, size_t ws_size,
                              hipStream_t stream) {
    const float* x     = (const float*)d_in[0];
    const float* scale = (const float*)d_in[1];
    const float* W     = (const float*)d_in[2];
    const float* bias  = (const float*)d_in[3];

    float* out   = (float*)d_out;
    float* edge  = out + OUT_ELEMS;
    float* basis = edge + EDGE_ELEMS;

    kan_kernel<<<dim3(256), dim3(512), SHMEM_BYTES, stream>>>(
        x, scale, W, bias, out, edge, basis);
}

// Round 13
// 37.934 us; speedup vs baseline: 1.2923x; 1.2923x over previous
//
#include <hip/hip_runtime.h>
#include <math.h>

#define NBATCH 8192
#define NIN 64
#define NOUT 64
#define NG 17

typedef float f32x4 __attribute__((ext_vector_type(4)));

// d_out layout (flat, f32): output[8192*64] | edge[8192*64*64] | basis[8192*64*17]
#define OUT_ELEMS   (NBATCH * NOUT)
#define EDGE_ELEMS  (NBATCH * NIN * NOUT)
#define WT_FLOATS   (NIN * NG * NOUT)
#define WT_BYTES    (WT_FLOATS * sizeof(float))

__global__ void kan_transpose_w(const float* __restrict__ W, float* __restrict__ Wt) {
    int idx = blockIdx.x * blockDim.x + threadIdx.x;
    if (idx >= NIN * NOUT * NG) return;
    int i   = idx / (NOUT * NG);
    int rem = idx - i * (NOUT * NG);
    int o   = rem / NG;
    int g   = rem - o * NG;
    Wt[(i * NG + g) * NOUT + o] = W[idx];
}

// 8 waves/block = 8 rows; scale in LDS; UNCONDITIONAL clamped Wt loads with
// 1-deep software pipeline so stores are never gated on the current loads.
__global__ __launch_bounds__(512) void kan_kernel(
    const float* __restrict__ x,      // [B, 64]
    const float* __restrict__ scale,  // [64, 64]
    const float* __restrict__ Wt,     // [64, 17, 64] (transposed)
    const float* __restrict__ bias,   // [64]
    float* __restrict__ out,          // [B, 64]
    float* __restrict__ edge,         // [B, 64, 64]
    float* __restrict__ basis)        // [B, 64, 17]
{
    const int tid  = threadIdx.x;
    const int wave = tid >> 6;
    const int lane = tid & 63;
    const int b = blockIdx.x * 8 + wave;

    __shared__ float s_scale[NIN * NOUT];   // 16 KB
    __shared__ f32x4 s_meta[8][64];         // {silu, tw0, tw1, bits(g0c|g1c<<16)} 8 KB

    // ---- stage scale into LDS ----
    {
        const f32x4* s4 = (const f32x4*)scale;
        f32x4* d4 = (f32x4*)s_scale;
        d4[tid]       = s4[tid];
        d4[tid + 512] = s4[tid + 512];
    }

    // ---- phase 1: per-input meta (lane == i), masked weights + clamped idx ----
    {
        float xv  = x[b * NIN + lane];
        float sig = 1.0f / (1.0f + __expf(-xv));
        float sl  = xv * sig;
        float u   = (xv + 2.5f) * 3.2f;       // spacing = 5/16 exact
        float g0f = floorf(u);
        float t   = u - g0f;
        int   g0  = (int)g0f;
        float tw0 = ((unsigned)g0       < 17u) ? (1.0f - t) : 0.0f;
        float tw1 = ((unsigned)(g0 + 1) < 17u) ? t          : 0.0f;
        int g0c = min(max(g0, 0), 16);
        int g1c = min(max(g0 + 1, 0), 16);
        f32x4 m;
        m.x = sl; m.y = tw0; m.z = tw1;
        m.w = __uint_as_float((unsigned)g0c | ((unsigned)g1c << 16));
        s_meta[wave][lane] = m;
    }
    __syncthreads();

    // ---- phase 2: basis writes (272 f32x4 per row), pure stores ----
    {
        float* brow = basis + (size_t)b * (NIN * NG);
        #pragma unroll
        for (int k = 0; k < 4; ++k) {
            int p0 = (k * 64 + lane) * 4;
            f32x4 v;
            #pragma unroll
            for (int e = 0; e < 4; ++e) {
                int p = p0 + e;
                int i = (int)((unsigned)p / 17u);
                int g = p - i * 17;
                f32x4 m = s_meta[wave][i];
                unsigned gg = __float_as_uint(m.w);
                int g0c = (int)(gg & 0xffffu);
                int g1c = (int)(gg >> 16);
                v[e] = ((g == g0c) ? m.y : 0.0f) + ((g == g1c) ? m.z : 0.0f);
            }
            *(f32x4*)(brow + p0) = v;
        }
        if (lane < 16) {
            int p0 = (256 + lane) * 4;
            f32x4 v;
            #pragma unroll
            for (int e = 0; e < 4; ++e) {
                int p = p0 + e;
                int i = (int)((unsigned)p / 17u);
                int g = p - i * 17;
                f32x4 m = s_meta[wave][i];
                unsigned gg = __float_as_uint(m.w);
                int g0c = (int)(gg & 0xffffu);
                int g1c = (int)(gg >> 16);
                v[e] = ((g == g0c) ? m.y : 0.0f) + ((g == g1c) ? m.z : 0.0f);
            }
            *(f32x4*)(brow + p0) = v;
        }
    }

    // ---- phase 3: edge stores, 1-deep pipelined unconditional Wt loads ----
    f32x4 acc = {0.f, 0.f, 0.f, 0.f};
    float* erow = edge + (size_t)b * (NIN * NOUT);
    const int iq = lane >> 4;
    const int o  = (lane & 15) * 4;

    f32x4 m_n = s_meta[wave][iq];
    unsigned gg_n = __float_as_uint(m_n.w);
    f32x4 w0_n = *(const f32x4*)(Wt + (iq * NG + (int)(gg_n & 0xffffu)) * NOUT + o);
    f32x4 w1_n = *(const f32x4*)(Wt + (iq * NG + (int)(gg_n >> 16))     * NOUT + o);

    #pragma unroll
    for (int ib = 0; ib < NIN; ib += 4) {
        f32x4 m  = m_n;
        f32x4 w0 = w0_n;
        f32x4 w1 = w1_n;
        if (ib + 4 < NIN) {               // issue NEXT iter's loads first
            int i = ib + 4 + iq;
            m_n = s_meta[wave][i];
            unsigned gg = __float_as_uint(m_n.w);
            w0_n = *(const f32x4*)(Wt + (i * NG + (int)(gg & 0xffffu)) * NOUT + o);
            w1_n = *(const f32x4*)(Wt + (i * NG + (int)(gg >> 16))     * NOUT + o);
        }
        f32x4 sc = *(const f32x4*)(s_scale + (ib + iq) * NOUT + o);
        f32x4 v = m.x * sc + m.y * w0 + m.z * w1;
        *(f32x4*)(erow + ib * NOUT + lane * 4) = v;   // 1KB contiguous per wave
        acc += v;
    }
    #pragma unroll
    for (int e = 0; e < 4; ++e) {
        float a = acc[e];
        a += __shfl_xor(a, 16);
        a += __shfl_xor(a, 32);
        acc[e] = a;
    }
    if (lane < 16) {
        f32x4 bi = *(const f32x4*)(bias + lane * 4);
        f32x4 r = acc * 0.125f + bi;      // 1/sqrt(64) = 0.125 exact
        *(f32x4*)(out + (size_t)b * NOUT + lane * 4) = r;
    }
}

extern "C" void kernel_launch(void* const* d_in, const int* in_sizes, int n_in,
                              void* d_out, int out_size, void* d_ws, size_t ws_size,
                              hipStream_t stream) {
    const float* x     = (const float*)d_in[0];
    const float* scale = (const float*)d_in[1];
    const float* W     = (const float*)d_in[2];
    const float* bias  = (const float*)d_in[3];

    float* out   = (float*)d_out;
    float* edge  = out + OUT_ELEMS;
    float* basis = edge + EDGE_ELEMS;

    float* Wt = (float*)d_ws;
    const int n = NIN * NOUT * NG;
    if (ws_size >= WT_BYTES) {
        kan_transpose_w<<<(n + 255) / 256, 256, 0, stream>>>(W, Wt);
        kan_kernel<<<dim3(NBATCH / 8), dim3(512), 0, stream>>>(x, scale, Wt, bias, out, edge, basis);
    }
}